// Round 1
// baseline (1468.989 us; speedup 1.0000x reference)
//
#include <hip/hip_runtime.h>

// GCN_56521769616159: 3-prop shared-weight GCN, N=100k, E=1.6M, 128->64 feats.
// Pipeline: deg/dinv -> GEMM1(in@lin_w+b -> h,ori) -> 3x { [LN(h+ori),relu] ->
//           hw=h@conv_w -> agg=selfloop+bias init -> edge scatter-atomics }.
// fp32 throughout (no fp32 MFMA on CDNA4; GEMMs are minor vs edge scatter).

static constexpr int NN    = 100000;
static constexpr int NEDGE = 1600000;
static constexpr int HF    = 64;
#define EPSV 1e-5f

__global__ __launch_bounds__(256) void k_fill1(float* __restrict__ deg) {
    int i = blockIdx.x * 256 + threadIdx.x;
    if (i < NN) deg[i] = 1.0f;   // self-loop contributes 1 to every node's degree
}

__global__ __launch_bounds__(256) void k_deg(const int* __restrict__ ei,
                                             float* __restrict__ deg) {
    int e = blockIdx.x * 256 + threadIdx.x;
    if (e < NEDGE) atomicAdd(&deg[ei[NEDGE + e]], 1.0f);  // dst row of edge_index
}

__global__ __launch_bounds__(256) void k_dinv(float* __restrict__ deg) {
    int i = blockIdx.x * 256 + threadIdx.x;
    if (i < NN) deg[i] = rsqrtf(fmaxf(deg[i], 1.0f));
}

// Tiled fp32 GEMM: out[N,64] = A[N,K] @ W[K,64] (+bias). 64-row x 64-col tile,
// 256 threads, each thread 4x4 outputs. K in {128, 64}. DUAL writes two copies.
template<int K, bool DUAL, bool BIAS>
__global__ __launch_bounds__(256) void k_gemm(const float* __restrict__ A,
                                              const float* __restrict__ W,
                                              const float* __restrict__ bias,
                                              float* __restrict__ out0,
                                              float* __restrict__ out1)
{
    __shared__ float As[64][65];   // +1 pad: scalar broadcast reads conflict-free
    __shared__ float Ws[64][64];   // float4 reads, 2-way conflict (free)
    const int tid = threadIdx.x;
    const int tx = tid & 15, ty = tid >> 4;
    const int c0 = tx * 4, r0 = ty * 4;
    const int row0 = blockIdx.x * 64;
    float acc[4][4] = {};

    for (int kt = 0; kt < K / 64; ++kt) {
        #pragma unroll
        for (int q = 0; q < 4; ++q) {
            int vid = q * 256 + tid;          // 1024 float4s = 64x64 tile
            int row = vid >> 4;
            int kq  = vid & 15;
            if (row0 + row < NN) {
                float4 v = *reinterpret_cast<const float4*>(
                    &A[(size_t)(row0 + row) * K + kt * 64 + kq * 4]);
                As[row][kq * 4 + 0] = v.x; As[row][kq * 4 + 1] = v.y;
                As[row][kq * 4 + 2] = v.z; As[row][kq * 4 + 3] = v.w;
            }
            *reinterpret_cast<float4*>(&Ws[row][kq * 4]) =
                *reinterpret_cast<const float4*>(&W[(size_t)(kt * 64 + row) * HF + kq * 4]);
        }
        __syncthreads();
        #pragma unroll 8
        for (int k = 0; k < 64; ++k) {
            float4 wv = *reinterpret_cast<const float4*>(&Ws[k][c0]);
            float a0 = As[r0 + 0][k], a1 = As[r0 + 1][k];
            float a2 = As[r0 + 2][k], a3 = As[r0 + 3][k];
            acc[0][0] += a0 * wv.x; acc[0][1] += a0 * wv.y; acc[0][2] += a0 * wv.z; acc[0][3] += a0 * wv.w;
            acc[1][0] += a1 * wv.x; acc[1][1] += a1 * wv.y; acc[1][2] += a1 * wv.z; acc[1][3] += a1 * wv.w;
            acc[2][0] += a2 * wv.x; acc[2][1] += a2 * wv.y; acc[2][2] += a2 * wv.z; acc[2][3] += a2 * wv.w;
            acc[3][0] += a3 * wv.x; acc[3][1] += a3 * wv.y; acc[3][2] += a3 * wv.z; acc[3][3] += a3 * wv.w;
        }
        __syncthreads();
    }

    float4 bv = make_float4(0.f, 0.f, 0.f, 0.f);
    if (BIAS) bv = *reinterpret_cast<const float4*>(&bias[c0]);
    #pragma unroll
    for (int i = 0; i < 4; ++i) {
        int r = row0 + r0 + i;
        if (r < NN) {
            float4 o = make_float4(acc[i][0] + bv.x, acc[i][1] + bv.y,
                                   acc[i][2] + bv.z, acc[i][3] + bv.w);
            *reinterpret_cast<float4*>(&out0[(size_t)r * HF + c0]) = o;
            if (DUAL)
                *reinterpret_cast<float4*>(&out1[(size_t)r * HF + c0]) = o;
        }
    }
}

// h = relu(layernorm(h + ori, lnw, lnb)); one 64-lane wave per row.
__global__ __launch_bounds__(256) void k_preop(float* __restrict__ h,
                                               const float* __restrict__ ori,
                                               const float* __restrict__ lnw,
                                               const float* __restrict__ lnb)
{
    int row  = blockIdx.x * 4 + (threadIdx.x >> 6);
    int lane = threadIdx.x & 63;
    if (row >= NN) return;
    size_t idx = (size_t)row * HF + lane;
    float v = h[idx] + ori[idx];
    float s = v;
    #pragma unroll
    for (int off = 32; off > 0; off >>= 1) s += __shfl_xor(s, off);
    float mu = s * (1.0f / 64.0f);
    float d = v - mu;
    float q = d * d;
    #pragma unroll
    for (int off = 32; off > 0; off >>= 1) q += __shfl_xor(q, off);
    float y = d * rsqrtf(q * (1.0f / 64.0f) + EPSV) * lnw[lane] + lnb[lane];
    h[idx] = fmaxf(y, 0.0f);
}

// out[i][f] = hw[i][f]*dinv[i]^2 + conv_b[f]  (self-loop term + bias; also
// initializes the whole agg buffer so scatter can atomically accumulate).
__global__ __launch_bounds__(256) void k_agginit(const float* __restrict__ hw,
                                                 const float* __restrict__ dinv,
                                                 const float* __restrict__ cb,
                                                 float* __restrict__ out)
{
    int row  = blockIdx.x * 4 + (threadIdx.x >> 6);
    int lane = threadIdx.x & 63;
    if (row >= NN) return;
    float di = dinv[row];
    out[(size_t)row * HF + lane] = hw[(size_t)row * HF + lane] * di * di + cb[lane];
}

// One 64-lane wave per edge: gather hw[src] row (256B coalesced), scale by
// dinv[src]*dinv[dst], atomicAdd into out[dst] row.
__global__ __launch_bounds__(256) void k_scatter(const int* __restrict__ ei,
                                                 const float* __restrict__ dinv,
                                                 const float* __restrict__ hw,
                                                 float* __restrict__ out)
{
    int e = blockIdx.x * 4 + (threadIdx.x >> 6);
    if (e >= NEDGE) return;
    int lane = threadIdx.x & 63;
    int s = ei[e];
    int d = ei[NEDGE + e];
    float coef = dinv[s] * dinv[d];
    float v = hw[(size_t)s * HF + lane] * coef;
    atomicAdd(&out[(size_t)d * HF + lane], v);
}

extern "C" void kernel_launch(void* const* d_in, const int* in_sizes, int n_in,
                              void* d_out, int out_size, void* d_ws, size_t ws_size,
                              hipStream_t stream)
{
    const float* in_feat = (const float*)d_in[0];
    const int*   ei      = (const int*)d_in[1];   // [2][E] int32
    const float* lin_w   = (const float*)d_in[2];
    const float* lin_b   = (const float*)d_in[3];
    const float* conv_w  = (const float*)d_in[4];
    const float* conv_b  = (const float*)d_in[5];
    const float* ln_w    = (const float*)d_in[6]; // [3][64]
    const float* ln_b    = (const float*)d_in[7];
    float* out = (float*)d_out;
    float* ws  = (float*)d_ws;

    // Workspace layout (floats): dinv[100352 pad] | h[6.4M] | ori[6.4M] | hw[6.4M]
    float* dinv = ws;
    float* h    = ws + 100352;
    float* ori  = h + (size_t)NN * HF;
    float* hw   = ori + (size_t)NN * HF;

    // Degree + normalization coefficients
    k_fill1<<<(NN + 255) / 256, 256, 0, stream>>>(dinv);
    k_deg<<<(NEDGE + 255) / 256, 256, 0, stream>>>(ei, dinv);
    k_dinv<<<(NN + 255) / 256, 256, 0, stream>>>(dinv);

    // h = ori = in_feat @ lin_w + lin_b
    k_gemm<128, true, true><<<(NN + 63) / 64, 256, 0, stream>>>(
        in_feat, lin_w, lin_b, h, ori);

    for (int it = 0; it < 3; ++it) {
        if (it)
            k_preop<<<(NN + 3) / 4, 256, 0, stream>>>(h, ori, ln_w + it * HF, ln_b + it * HF);
        // hw = h @ conv_w   (bias deferred to agginit)
        k_gemm<64, false, false><<<(NN + 63) / 64, 256, 0, stream>>>(
            h, conv_w, nullptr, hw, nullptr);
        float* tgt = (it == 2) ? out : h;   // h consumed by GEMM2; safe to overwrite
        k_agginit<<<(NN + 3) / 4, 256, 0, stream>>>(hw, dinv, conv_b, tgt);
        k_scatter<<<(NEDGE + 3) / 4, 256, 0, stream>>>(ei, dinv, hw, tgt);
    }
}

// Round 2
// 595.428 us; speedup vs baseline: 2.4671x; 2.4671x over previous
//
#include <hip/hip_runtime.h>

// GCN_56521769616159 R2: replace edge scatter-atomics (400MB HBM write-through
// per pass) with per-call CSR-by-dst build + register-accumulating gather.
// LN+residual+ReLU fused into gather epilogue.

static constexpr int NN  = 100000;
static constexpr int NE  = 1600000;
static constexpr int HF  = 64;
static constexpr int NNP = 100352;   // padded NN (multiple of 256)
#define EPSV 1e-5f

__global__ __launch_bounds__(256) void k_zero(int* __restrict__ c) {
    int i = blockIdx.x * 256 + threadIdx.x;
    if (i < NN) c[i] = 0;
}

// Histogram of dst (in-degree without self-loop).
__global__ __launch_bounds__(256) void k_hist(const int* __restrict__ ei,
                                              int* __restrict__ cnt) {
    int e = blockIdx.x * 256 + threadIdx.x;
    if (e < NE) atomicAdd(&cnt[ei[NE + e]], 1);
}

// Per-block Hillis-Steele scan: cnt -> exclusive-within-block rowp, totals -> bsum.
__global__ __launch_bounds__(256) void k_scan1(const int* __restrict__ cnt,
                                               int* __restrict__ rowp,
                                               int* __restrict__ bsum) {
    __shared__ int sm[256];
    int i = blockIdx.x * 256 + threadIdx.x;
    int x = (i < NN) ? cnt[i] : 0;
    sm[threadIdx.x] = x;
    __syncthreads();
    int v = x;
    for (int off = 1; off < 256; off <<= 1) {
        int t = (threadIdx.x >= (unsigned)off) ? sm[threadIdx.x - off] : 0;
        __syncthreads();
        v += t;
        sm[threadIdx.x] = v;
        __syncthreads();
    }
    if (i < NN) rowp[i] = v - x;
    if (threadIdx.x == 255) bsum[blockIdx.x] = v;
}

// Single-block scan of the 391 block totals -> exclusive offsets.
__global__ __launch_bounds__(512) void k_scan2(int* __restrict__ bsum, int nb) {
    __shared__ int sm[512];
    int t = threadIdx.x;
    int x = (t < nb) ? bsum[t] : 0;
    sm[t] = x;
    __syncthreads();
    int v = x;
    for (int off = 1; off < 512; off <<= 1) {
        int tt = (t >= off) ? sm[t - off] : 0;
        __syncthreads();
        v += tt;
        sm[t] = v;
        __syncthreads();
    }
    if (t < nb) bsum[t] = v - x;
}

// Finalize: rowp global exclusive scan; cur = rowp (cur aliases cnt);
// dinv = rsqrt(deg+1). One thread writes rowp[NN] = NE.
__global__ __launch_bounds__(256) void k_scan3(const int* cntIn, int* cur,
                                               int* __restrict__ rowp,
                                               const int* __restrict__ bsum,
                                               float* __restrict__ dinv) {
    int i = blockIdx.x * 256 + threadIdx.x;
    if (i < NN) {
        int c = cntIn[i];                 // read before aliased write below
        int r = rowp[i] + bsum[blockIdx.x];
        rowp[i] = r;
        cur[i]  = r;
        dinv[i] = rsqrtf((float)c + 1.0f);  // self-loop adds 1; deg >= 1
    }
    if (i == 0) rowp[NN] = NE;
}

// Scatter edges into CSR order (arbitrary order within a dst bucket).
__global__ __launch_bounds__(256) void k_fillcsr(const int* __restrict__ ei,
                                                 int* __restrict__ cur,
                                                 int* __restrict__ es) {
    int e = blockIdx.x * 256 + threadIdx.x;
    if (e >= NE) return;
    int s = ei[e];
    int d = ei[NE + e];
    int pos = atomicAdd(&cur[d], 1);
    es[pos] = s;
}

// Tiled fp32 GEMM: out[N,64] = A[N,K] @ W[K,64] (+bias). 64x64 tile, 256 thr,
// 4x4 outputs/thread. DUAL writes two copies (h and ori).
template<int K, bool DUAL, bool BIAS>
__global__ __launch_bounds__(256) void k_gemm(const float* __restrict__ A,
                                              const float* __restrict__ W,
                                              const float* __restrict__ bias,
                                              float* __restrict__ out0,
                                              float* __restrict__ out1)
{
    __shared__ float As[64][65];
    __shared__ float Ws[64][64];
    const int tid = threadIdx.x;
    const int tx = tid & 15, ty = tid >> 4;
    const int c0 = tx * 4, r0 = ty * 4;
    const int row0 = blockIdx.x * 64;
    float acc[4][4] = {};

    for (int kt = 0; kt < K / 64; ++kt) {
        #pragma unroll
        for (int q = 0; q < 4; ++q) {
            int vid = q * 256 + tid;
            int row = vid >> 4;
            int kq  = vid & 15;
            if (row0 + row < NN) {
                float4 v = *reinterpret_cast<const float4*>(
                    &A[(size_t)(row0 + row) * K + kt * 64 + kq * 4]);
                As[row][kq * 4 + 0] = v.x; As[row][kq * 4 + 1] = v.y;
                As[row][kq * 4 + 2] = v.z; As[row][kq * 4 + 3] = v.w;
            }
            *reinterpret_cast<float4*>(&Ws[row][kq * 4]) =
                *reinterpret_cast<const float4*>(&W[(size_t)(kt * 64 + row) * HF + kq * 4]);
        }
        __syncthreads();
        #pragma unroll 8
        for (int k = 0; k < 64; ++k) {
            float4 wv = *reinterpret_cast<const float4*>(&Ws[k][c0]);
            float a0 = As[r0 + 0][k], a1 = As[r0 + 1][k];
            float a2 = As[r0 + 2][k], a3 = As[r0 + 3][k];
            acc[0][0] += a0 * wv.x; acc[0][1] += a0 * wv.y; acc[0][2] += a0 * wv.z; acc[0][3] += a0 * wv.w;
            acc[1][0] += a1 * wv.x; acc[1][1] += a1 * wv.y; acc[1][2] += a1 * wv.z; acc[1][3] += a1 * wv.w;
            acc[2][0] += a2 * wv.x; acc[2][1] += a2 * wv.y; acc[2][2] += a2 * wv.z; acc[2][3] += a2 * wv.w;
            acc[3][0] += a3 * wv.x; acc[3][1] += a3 * wv.y; acc[3][2] += a3 * wv.z; acc[3][3] += a3 * wv.w;
        }
        __syncthreads();
    }

    float4 bv = make_float4(0.f, 0.f, 0.f, 0.f);
    if (BIAS) bv = *reinterpret_cast<const float4*>(&bias[c0]);
    #pragma unroll
    for (int i = 0; i < 4; ++i) {
        int r = row0 + r0 + i;
        if (r < NN) {
            float4 o = make_float4(acc[i][0] + bv.x, acc[i][1] + bv.y,
                                   acc[i][2] + bv.z, acc[i][3] + bv.w);
            *reinterpret_cast<float4*>(&out0[(size_t)r * HF + c0]) = o;
            if (DUAL)
                *reinterpret_cast<float4*>(&out1[(size_t)r * HF + c0]) = o;
        }
    }
}

// One wave per dst node: acc = selfloop + bias + sum over CSR edges of
// coef * hw[src][lane]. FUSE_LN: epilogue applies residual+LN+ReLU (produces
// next iteration's h). Else writes raw conv output (final -> d_out).
template<int FUSE_LN>
__global__ __launch_bounds__(256) void k_gather(const int* __restrict__ rowp,
                                                const int* __restrict__ es,
                                                const float* __restrict__ dinv,
                                                const float* __restrict__ hw,
                                                const float* __restrict__ cb,
                                                const float* __restrict__ ori,
                                                const float* __restrict__ lnw,
                                                const float* __restrict__ lnb,
                                                float* __restrict__ out)
{
    int row = blockIdx.x * 4 + (threadIdx.x >> 6);
    if (row >= NN) return;                       // wave-uniform
    int lane = threadIdx.x & 63;
    float dd = dinv[row];
    float acc = hw[(size_t)row * HF + lane] * dd * dd + cb[lane];

    int start = rowp[row], end = rowp[row + 1];
    for (int base = start; base < end; base += 64) {
        int n = end - base;
        if (n > 64) n = 64;
        int   sl = 0;
        float cl = 0.0f;
        if (lane < n) {
            sl = es[base + lane];
            cl = dinv[sl] * dd;
        }
        int j = 0;
        for (; j + 4 <= n; j += 4) {
            int   s0 = __shfl(sl, j),     s1 = __shfl(sl, j + 1);
            int   s2 = __shfl(sl, j + 2), s3 = __shfl(sl, j + 3);
            float c0 = __shfl(cl, j),     c1 = __shfl(cl, j + 1);
            float c2 = __shfl(cl, j + 2), c3 = __shfl(cl, j + 3);
            float v0 = hw[(size_t)s0 * HF + lane];
            float v1 = hw[(size_t)s1 * HF + lane];
            float v2 = hw[(size_t)s2 * HF + lane];
            float v3 = hw[(size_t)s3 * HF + lane];
            acc += v0 * c0 + v1 * c1 + v2 * c2 + v3 * c3;
        }
        for (; j < n; ++j) {
            int   s0 = __shfl(sl, j);
            float c0 = __shfl(cl, j);
            acc += hw[(size_t)s0 * HF + lane] * c0;
        }
    }

    size_t idx = (size_t)row * HF + lane;
    if (FUSE_LN) {
        float v = acc + ori[idx];
        float s = v;
        #pragma unroll
        for (int off = 32; off > 0; off >>= 1) s += __shfl_xor(s, off);
        float mu = s * (1.0f / 64.0f);
        float d = v - mu;
        float q = d * d;
        #pragma unroll
        for (int off = 32; off > 0; off >>= 1) q += __shfl_xor(q, off);
        float y = d * rsqrtf(q * (1.0f / 64.0f) + EPSV) * lnw[lane] + lnb[lane];
        out[idx] = fmaxf(y, 0.0f);
    } else {
        out[idx] = acc;
    }
}

extern "C" void kernel_launch(void* const* d_in, const int* in_sizes, int n_in,
                              void* d_out, int out_size, void* d_ws, size_t ws_size,
                              hipStream_t stream)
{
    const float* in_feat = (const float*)d_in[0];
    const int*   ei      = (const int*)d_in[1];   // [2][E]
    const float* lin_w   = (const float*)d_in[2];
    const float* lin_b   = (const float*)d_in[3];
    const float* conv_w  = (const float*)d_in[4];
    const float* conv_b  = (const float*)d_in[5];
    const float* ln_w    = (const float*)d_in[6]; // [3][64]
    const float* ln_b    = (const float*)d_in[7];
    float* out = (float*)d_out;
    float* ws  = (float*)d_ws;

    // Workspace layout (84.4 MB):
    float* dinv = ws;                        // NNP floats
    int*   cnt  = (int*)(ws + NNP);          // NNP ints (aliased as `cur` later)
    int*   rowp = cnt + NNP;                 // NNP ints (rowp[NN] = NE)
    int*   bsum = rowp + NNP;                // 1024 ints
    int*   es   = bsum + 1024;               // NE ints (CSR src list)
    float* h    = (float*)(es + NE);         // NN*HF
    float* ori  = h + (size_t)NN * HF;       // NN*HF
    float* hw   = ori + (size_t)NN * HF;     // NN*HF

    const int NB = (NN + 255) / 256;         // 391

    // ---- CSR build + dinv ----
    k_zero<<<NB, 256, 0, stream>>>(cnt);
    k_hist<<<NE / 256, 256, 0, stream>>>(ei, cnt);
    k_scan1<<<NB, 256, 0, stream>>>(cnt, rowp, bsum);
    k_scan2<<<1, 512, 0, stream>>>(bsum, NB);
    k_scan3<<<NB, 256, 0, stream>>>(cnt, cnt /*cur*/, rowp, bsum, dinv);
    k_fillcsr<<<NE / 256, 256, 0, stream>>>(ei, cnt /*cur*/, es);

    // ---- h = ori = in_feat @ lin_w + lin_b ----
    k_gemm<128, true, true><<<(NN + 63) / 64, 256, 0, stream>>>(
        in_feat, lin_w, lin_b, h, ori);

    // ---- 3 propagation steps ----
    for (int it = 0; it < 3; ++it) {
        k_gemm<64, false, false><<<(NN + 63) / 64, 256, 0, stream>>>(
            h, conv_w, nullptr, hw, nullptr);
        if (it < 2) {
            // gather + fused (residual + LN[it+1] + relu) -> next h
            k_gather<1><<<(NN + 3) / 4, 256, 0, stream>>>(
                rowp, es, dinv, hw, conv_b, ori,
                ln_w + (it + 1) * HF, ln_b + (it + 1) * HF, h);
        } else {
            k_gather<0><<<(NN + 3) / 4, 256, 0, stream>>>(
                rowp, es, dinv, hw, conv_b, nullptr, nullptr, nullptr, out);
        }
    }
}